// Round 5
// baseline (7740.240 us; speedup 1.0000x reference)
//
#include <hip/hip_runtime.h>
#include <hip/hip_bf16.h>
#include <hip/hip_fp16.h>

// GRU forward, MI355X. Harness gives f32 buffers (reference f16 -> f32).
// x:(512,64,1024) h0:(1,64,1024) w_ih,w_hh:(3072,1024) b:(3072) y:(512,64,1024).
//
// Round 8: f32 gi (reference keeps gi f32). PASSED 0.0078, scan 4530 us.
// Round 9: nt-loads/stores bundle FAILED (stale data; nt bypasses the
//          coherence path holding freshly-written gi/Y lines). Reverted.
// Round 10: register h-preload + reg h-chain: passed, but NO speedup
//          (8.87 us/step unchanged) -- sync protocol dominates, not loads.
// Round 11 (this round): per-BAND sync. Wave w of every block computes and
// consumes ONLY rows [16w,16w+16) of h -- the 4 row-bands are independent
// recurrences. So:
//  - no __syncthreads in the scan loop at all;
//  - each wave drains its own stores (vmcnt(0) is per-wave, covers all
//    lanes) and fetch_adds a per-(t,band) counter (one 128B line);
//  - each wave polls ONLY its band's counter to 64 (single-line load,
//    lane0 + shfl broadcast) instead of 64 scattered flag lines;
//  - Y stores after the signal, hidden under the poll (normal cached).
// Arithmetic identical to round 10 => absmax identical (0.0078125).

typedef __attribute__((ext_vector_type(8))) _Float16 f16x8;
typedef __attribute__((ext_vector_type(4))) float f32x4;
typedef __attribute__((ext_vector_type(8))) float f32x8;

#define MFMA(a, b, c) __builtin_amdgcn_mfma_f32_16x16x32_f16((a), (b), (c), 0, 0, 0)

#define T_T 512
#define T_B 64
#define T_K 1024
#define T_N3 3072

__device__ float          g_gi[(size_t)T_T * T_B * T_N3];   // 402 MiB f32 gi
__device__ unsigned short g_hbf[(size_t)T_T * T_B * T_K];   // 64 MiB f16 h_t
__device__ unsigned       g_ctr[(size_t)T_T * 4 * 32];      // 128B-padded (t,band) counters

static __device__ __forceinline__ f16x8 cvt8(f32x8 v) {
    f16x8 r;
    #pragma unroll
    for (int i = 0; i < 8; ++i) r[i] = (_Float16)v[i];
    return r;
}
static __device__ __forceinline__ float sigmoidf_(float x) {
    return 1.0f / (1.0f + __expf(-x));
}
static __device__ __forceinline__ float tanhf_(float x) {
    return 2.0f / (1.0f + __expf(-2.0f * x)) - 1.0f;
}

__global__ __launch_bounds__(256) void reset_flags_k() {
    for (int i = threadIdx.x; i < T_T * 4 * 32; i += 256) g_ctr[i] = 0;
}

// ---------------------------------------------------------------------------
// Kernel 1: gi = X @ Wih^T + bih, f32 out. f16 MFMA (inputs exactly f16).
// ---------------------------------------------------------------------------
__global__ __launch_bounds__(256) void gi_gemm(
    const float* __restrict__ X,     // (32768, 1024) f32
    const float* __restrict__ W,     // (3072, 1024) f32
    const float* __restrict__ bih)   // (3072,) f32
{
    __shared__ unsigned short lA[128 * 32];
    __shared__ unsigned short lB[128 * 32];
    const int tid  = threadIdx.x;
    const int lane = tid & 63;
    const int wid  = tid >> 6;
    const int m0 = (blockIdx.x / 24) * 128;
    const int n0 = (blockIdx.x % 24) * 128;
    const int wm = wid >> 1, wn = wid & 1;

    f32x4 acc[4][4] = {};

    for (int k0 = 0; k0 < T_K; k0 += 32) {
        #pragma unroll
        for (int i = 0; i < 2; ++i) {
            int idx = tid + i * 256;
            int kc  = idx & 3;
            int row = idx >> 2;
            f32x8 va = *(const f32x8*)(X + (size_t)(m0 + row) * T_K + k0 + kc * 8);
            f32x8 vb = *(const f32x8*)(W + (size_t)(n0 + row) * T_K + k0 + kc * 8);
            *(f16x8*)((char*)lA + kc * 2048 + row * 16) = cvt8(va);
            *(f16x8*)((char*)lB + kc * 2048 + row * 16) = cvt8(vb);
        }
        __syncthreads();

        f16x8 a[4], b[4];
        #pragma unroll
        for (int mt = 0; mt < 4; ++mt) {
            int row = 64 * wm + 16 * mt + (lane & 15);
            a[mt] = *(const f16x8*)((const char*)lA + (lane >> 4) * 2048 + row * 16);
        }
        #pragma unroll
        for (int nt = 0; nt < 4; ++nt) {
            int row = 64 * wn + 16 * nt + (lane & 15);
            b[nt] = *(const f16x8*)((const char*)lB + (lane >> 4) * 2048 + row * 16);
        }
        #pragma unroll
        for (int mt = 0; mt < 4; ++mt)
            #pragma unroll
            for (int nt = 0; nt < 4; ++nt)
                acc[mt][nt] = MFMA(a[mt], b[nt], acc[mt][nt]);
        __syncthreads();
    }

    #pragma unroll
    for (int mt = 0; mt < 4; ++mt) {
        int rbase = m0 + 64 * wm + 16 * mt + (lane >> 4) * 4;
        #pragma unroll
        for (int nt = 0; nt < 4; ++nt) {
            int col = n0 + 64 * wn + 16 * nt + (lane & 15);
            float bv = bih[col];
            #pragma unroll
            for (int j = 0; j < 4; ++j)
                g_gi[(size_t)(rbase + j) * T_N3 + col] = acc[mt][nt][j] + bv;
        }
    }
}

// ---------------------------------------------------------------------------
// Kernel 2: persistent GRU scan. 64 blocks x 256 threads. Per-band
// (per-wave) fence-free message passing; no in-loop __syncthreads.
// ---------------------------------------------------------------------------
__global__ __launch_bounds__(256, 1) void gru_scan(
    const float* __restrict__ Whh,   // (3072,1024) f32
    const float* __restrict__ Bhh,   // (3072,) f32
    const float* __restrict__ H0,    // (64,1024) f32
    float* Y)                        // (512,64,1024) f32
{
    __shared__ unsigned short Wl[48 * 1024];  // 96 KiB f16
    const int tid  = threadIdx.x;
    const int lane = tid & 63;
    const int w    = tid >> 6;
    const int c0   = blockIdx.x * 16;

    for (int idx = tid; idx < 48 * 128; idx += 256) {
        int row = idx >> 7;                   // gate*16 + c
        int kc  = idx & 127;
        int gate = row >> 4, cc = row & 15;
        f32x8 v = *(const f32x8*)(Whh + (size_t)(gate * 1024 + c0 + cc) * T_K + kc * 8);
        *(f16x8*)((char*)Wl + kc * 768 + row * 16) = cvt8(v);
    }
    const int colL = c0 + (lane & 15);
    const float br = Bhh[colL];
    const float bz = Bhh[1024 + colL];
    const float bn = Bhh[2048 + colL];
    __syncthreads();   // Wl ready (read-only afterwards)

    const char* bbase = (const char*)Wl + (lane >> 4) * 768 + (lane & 15) * 16;

    // Preload gi for t = 0 (f32, normal cached loads).
    float pr[4], pz[4], pn[4];
    #pragma unroll
    for (int j = 0; j < 4; ++j) {
        int row = 16 * w + (lane >> 4) * 4 + j;
        pr[j] = g_gi[(size_t)row * T_N3 + colL];
        pz[j] = g_gi[(size_t)row * T_N3 + 1024 + colL];
        pn[j] = g_gi[(size_t)row * T_N3 + 2048 + colL];
    }

    // Per-thread h chain registers (f16-rounded values, kept as f32).
    float hreg[4];

    for (int t = 0; t < T_T; ++t) {
        f32x4 ar = {0.f, 0.f, 0.f, 0.f}, az = ar, an = ar;

        if (t == 0) {
            const float* abase =
                H0 + (size_t)(16 * w + (lane & 15)) * T_K + (lane >> 4) * 8;
            #pragma unroll 4
            for (int kk = 0; kk < 32; ++kk) {
                f16x8 af = cvt8(*(const f32x8*)(abase + kk * 32));
                const char* bb = bbase + kk * 3072;
                ar = MFMA(af, *(const f16x8*)(bb),       ar);
                az = MFMA(af, *(const f16x8*)(bb + 256), az);
                an = MFMA(af, *(const f16x8*)(bb + 512), an);
            }
        } else {
            const unsigned short* abase = g_hbf + (size_t)(t - 1) * (T_B * T_K)
                + (size_t)(16 * w + (lane & 15)) * T_K + (lane >> 4) * 8;
            #pragma unroll 8
            for (int kk = 0; kk < 32; ++kk) {
                f16x8 af = *(const f16x8*)(abase + kk * 32);
                const char* bb = bbase + kk * 3072;
                ar = MFMA(af, *(const f16x8*)(bb),       ar);
                az = MFMA(af, *(const f16x8*)(bb + 256), az);
                an = MFMA(af, *(const f16x8*)(bb + 512), an);
            }
        }

        #pragma unroll
        for (int j = 0; j < 4; ++j) {
            int row = 16 * w + (lane >> 4) * 4 + j;
            size_t off = (size_t)row * T_K + colL;
            float hp = (t == 0) ? H0[off] : hreg[j];
            float r = sigmoidf_(pr[j] + ar[j] + br);
            float z = sigmoidf_(pz[j] + az[j] + bz);
            float n = tanhf_(pn[j] + r * (an[j] + bn));
            float h = (1.0f - z) * n + z * hp;
            __half h16 = __float2half(h);         // reference: astype(f16)
            float  hq  = __half2float(h16);
            hreg[j] = hq;

            // f16 h -> g_hbf via packed u32 relaxed agent store (write-through).
            unsigned v16 = (unsigned)__half_as_ushort(h16);
            unsigned up  = __shfl_xor(v16, 1);
            if (!(lane & 1)) {
                unsigned packed = v16 | (up << 16);
                unsigned* dst = (unsigned*)(g_hbf + (size_t)t * (T_B * T_K) + off);
                __hip_atomic_store(dst, packed, __ATOMIC_RELAXED,
                                   __HIP_MEMORY_SCOPE_AGENT);
            }
        }

        unsigned* ctr = &g_ctr[((size_t)t * 4 + w) * 32];

        if (t + 1 < T_T) {
            // Per-wave drain: vmcnt(0) covers all 64 lanes' h stores of this
            // wave (the only writers of this band's columns in this block).
            asm volatile("s_waitcnt vmcnt(0)" ::: "memory");
            if (lane == 0)
                __hip_atomic_fetch_add(ctr, 1u, __ATOMIC_RELAXED,
                                       __HIP_MEMORY_SCOPE_AGENT);
        }

        // Y stores off the signal path (normal cached stores, hidden
        // under the poll). hreg[j] holds the f16-rounded value.
        #pragma unroll
        for (int j = 0; j < 4; ++j) {
            int row = 16 * w + (lane >> 4) * 4 + j;
            size_t off = (size_t)row * T_K + colL;
            Y[(size_t)t * (T_B * T_K) + off] = hreg[j];
        }

        if (t + 1 < T_T) {
            // Prefetch gi for t+1 while polling (normal cached loads).
            const float* g = g_gi + (size_t)(t + 1) * T_B * T_N3;
            #pragma unroll
            for (int j = 0; j < 4; ++j) {
                int row = 16 * w + (lane >> 4) * 4 + j;
                pr[j] = g[(size_t)row * T_N3 + colL];
                pz[j] = g[(size_t)row * T_N3 + 1024 + colL];
                pn[j] = g[(size_t)row * T_N3 + 2048 + colL];
            }

            // Poll own band's counter: all 64 block-contributions of band w.
            for (;;) {
                unsigned v = 0;
                if (lane == 0)
                    v = __hip_atomic_load(ctr, __ATOMIC_RELAXED,
                                          __HIP_MEMORY_SCOPE_AGENT);
                v = __shfl(v, 0);
                if (v >= 64u) break;
                __builtin_amdgcn_s_sleep(1);
            }
            asm volatile("" ::: "memory");
        }
    }
}

extern "C" void kernel_launch(void* const* d_in, const int* in_sizes, int n_in,
                              void* d_out, int out_size, void* d_ws, size_t ws_size,
                              hipStream_t stream)
{
    const float* X   = (const float*)d_in[0];
    const float* H0  = (const float*)d_in[1];
    const float* Wih = (const float*)d_in[2];
    const float* Whh = (const float*)d_in[3];
    const float* Bih = (const float*)d_in[4];
    const float* Bhh = (const float*)d_in[5];
    float* Y = (float*)d_out;
    (void)d_ws; (void)ws_size; (void)in_sizes; (void)n_in; (void)out_size;

    reset_flags_k<<<dim3(1), dim3(256), 0, stream>>>();

    gi_gemm<<<dim3(256 * 24), dim3(256), 0, stream>>>(X, Wih, Bih);

    gru_scan<<<dim3(64), dim3(256), 0, stream>>>(Whh, Bhh, H0, Y);
}

// Round 8
// 4980.199 us; speedup vs baseline: 1.5542x; 1.5542x over previous
//
#include <hip/hip_runtime.h>
#include <hip/hip_bf16.h>
#include <hip/hip_fp16.h>

// GRU forward, MI355X. Harness gives f32 buffers (reference f16 -> f32).
// x:(512,64,1024) h0:(1,64,1024) w_ih,w_hh:(3072,1024) b:(3072) y:(512,64,1024).
//
// PROTOCOL (round-2/4, twice-proven bit-deterministic, absmax 0.0078125):
// per-step: gate math writes Y (cached) then h (packed u32 RELAXED
// agent-scope write-through) inside the gate loop; s_waitcnt vmcnt(0);
// __syncthreads; tid0 stores flag (RELAXED agent, PRIVATE 128B line);
// gi prefetch; wave0 gather-polls all 64 flags with s_sleep backoff;
// __syncthreads.
//
// FROZEN BY EXPERIMENT (do not touch any of these):
//  - Y after flag store        -> absmax 0.117 (r3, r6 -- twice)
//  - nontemporal loads/stores  -> absmax 0.117 (r3)
//  - per-band fetch_add sync   -> absmax 0.048 + 7395us (r5)
//  - flags packed 4B stride    -> absmax 0.083 (r7): 64 blocks on 8
//    non-coherent XCD L2s false-sharing two lines; whole-line writebacks
//    clobber each other. 128B-per-flag padding is a CORRECTNESS feature.
//
// Round 15 (this round): re-bank the passing kernel. Scan byte-identical
// to round 4. ONE isolated change in the other dispatch: XCD-aware
// blockIdx swizzle in gi_gemm (6144%8==0 -> bijective chunked remap;
// same tiles, same arithmetic, bit-identical gi). Consecutive bids share
// the same 128-row X panel; chunking keeps them on one XCD's L2.

typedef __attribute__((ext_vector_type(8))) _Float16 f16x8;
typedef __attribute__((ext_vector_type(4))) float f32x4;
typedef __attribute__((ext_vector_type(8))) float f32x8;

#define MFMA(a, b, c) __builtin_amdgcn_mfma_f32_16x16x32_f16((a), (b), (c), 0, 0, 0)

#define T_T 512
#define T_B 64
#define T_K 1024
#define T_N3 3072

__device__ float          g_gi[(size_t)T_T * T_B * T_N3];   // 402 MiB f32 gi
__device__ unsigned short g_hbf[(size_t)T_T * T_B * T_K];   // 64 MiB f16 h_t
__device__ unsigned       g_flags[64 * 32];                 // 128B-padded flags

static __device__ __forceinline__ f16x8 cvt8(f32x8 v) {
    f16x8 r;
    #pragma unroll
    for (int i = 0; i < 8; ++i) r[i] = (_Float16)v[i];
    return r;
}
static __device__ __forceinline__ float sigmoidf_(float x) {
    return 1.0f / (1.0f + __expf(-x));
}
static __device__ __forceinline__ float tanhf_(float x) {
    return 2.0f / (1.0f + __expf(-2.0f * x)) - 1.0f;
}

__global__ __launch_bounds__(256) void reset_flags_k() {
    for (int i = threadIdx.x; i < 64 * 32; i += 256) g_flags[i] = 0;
}

// ---------------------------------------------------------------------------
// Kernel 1: gi = X @ Wih^T + bih, f32 out. f16 MFMA (inputs exactly f16).
// XCD-swizzled blockIdx (bijective: 6144 = 8 * 768).
// ---------------------------------------------------------------------------
__global__ __launch_bounds__(256) void gi_gemm(
    const float* __restrict__ X,     // (32768, 1024) f32
    const float* __restrict__ W,     // (3072, 1024) f32
    const float* __restrict__ bih)   // (3072,) f32
{
    __shared__ unsigned short lA[128 * 32];
    __shared__ unsigned short lB[128 * 32];
    const int tid  = threadIdx.x;
    const int lane = tid & 63;
    const int wid  = tid >> 6;
    // XCD-aware chunked swizzle: xcd = bid%8 gets contiguous chunk of 768.
    const int swz = (blockIdx.x & 7) * 768 + (blockIdx.x >> 3);
    const int m0 = (swz / 24) * 128;
    const int n0 = (swz % 24) * 128;
    const int wm = wid >> 1, wn = wid & 1;

    f32x4 acc[4][4] = {};

    for (int k0 = 0; k0 < T_K; k0 += 32) {
        #pragma unroll
        for (int i = 0; i < 2; ++i) {
            int idx = tid + i * 256;
            int kc  = idx & 3;
            int row = idx >> 2;
            f32x8 va = *(const f32x8*)(X + (size_t)(m0 + row) * T_K + k0 + kc * 8);
            f32x8 vb = *(const f32x8*)(W + (size_t)(n0 + row) * T_K + k0 + kc * 8);
            *(f16x8*)((char*)lA + kc * 2048 + row * 16) = cvt8(va);
            *(f16x8*)((char*)lB + kc * 2048 + row * 16) = cvt8(vb);
        }
        __syncthreads();

        f16x8 a[4], b[4];
        #pragma unroll
        for (int mt = 0; mt < 4; ++mt) {
            int row = 64 * wm + 16 * mt + (lane & 15);
            a[mt] = *(const f16x8*)((const char*)lA + (lane >> 4) * 2048 + row * 16);
        }
        #pragma unroll
        for (int nt = 0; nt < 4; ++nt) {
            int row = 64 * wn + 16 * nt + (lane & 15);
            b[nt] = *(const f16x8*)((const char*)lB + (lane >> 4) * 2048 + row * 16);
        }
        #pragma unroll
        for (int mt = 0; mt < 4; ++mt)
            #pragma unroll
            for (int nt = 0; nt < 4; ++nt)
                acc[mt][nt] = MFMA(a[mt], b[nt], acc[mt][nt]);
        __syncthreads();
    }

    #pragma unroll
    for (int mt = 0; mt < 4; ++mt) {
        int rbase = m0 + 64 * wm + 16 * mt + (lane >> 4) * 4;
        #pragma unroll
        for (int nt = 0; nt < 4; ++nt) {
            int col = n0 + 64 * wn + 16 * nt + (lane & 15);
            float bv = bih[col];
            #pragma unroll
            for (int j = 0; j < 4; ++j)
                g_gi[(size_t)(rbase + j) * T_N3 + col] = acc[mt][nt][j] + bv;
        }
    }
}

// ---------------------------------------------------------------------------
// Kernel 2: persistent GRU scan. 64 blocks x 256 threads, fence-free
// message passing. BYTE-IDENTICAL to round 4 (the proven passer).
// ---------------------------------------------------------------------------
__global__ __launch_bounds__(256, 1) void gru_scan(
    const float* __restrict__ Whh,   // (3072,1024) f32
    const float* __restrict__ Bhh,   // (3072,) f32
    const float* __restrict__ H0,    // (64,1024) f32
    float* Y)                        // (512,64,1024) f32
{
    __shared__ unsigned short Wl[48 * 1024];  // 96 KiB f16
    const int tid  = threadIdx.x;
    const int lane = tid & 63;
    const int w    = tid >> 6;
    const int c0   = blockIdx.x * 16;

    for (int idx = tid; idx < 48 * 128; idx += 256) {
        int row = idx >> 7;                   // gate*16 + c
        int kc  = idx & 127;
        int gate = row >> 4, cc = row & 15;
        f32x8 v = *(const f32x8*)(Whh + (size_t)(gate * 1024 + c0 + cc) * T_K + kc * 8);
        *(f16x8*)((char*)Wl + kc * 768 + row * 16) = cvt8(v);
    }
    const int colL = c0 + (lane & 15);
    const float br = Bhh[colL];
    const float bz = Bhh[1024 + colL];
    const float bn = Bhh[2048 + colL];
    __syncthreads();

    const char* bbase = (const char*)Wl + (lane >> 4) * 768 + (lane & 15) * 16;

    // Preload gi for t = 0 (f32, normal cached loads).
    float pr[4], pz[4], pn[4];
    #pragma unroll
    for (int j = 0; j < 4; ++j) {
        int row = 16 * w + (lane >> 4) * 4 + j;
        pr[j] = g_gi[(size_t)row * T_N3 + colL];
        pz[j] = g_gi[(size_t)row * T_N3 + 1024 + colL];
        pn[j] = g_gi[(size_t)row * T_N3 + 2048 + colL];
    }

    // Per-thread h chain registers (f16-rounded values, kept as f32).
    float hreg[4];

    for (int t = 0; t < T_T; ++t) {
        f32x4 ar = {0.f, 0.f, 0.f, 0.f}, az = ar, an = ar;

        if (t == 0) {
            const float* abase =
                H0 + (size_t)(16 * w + (lane & 15)) * T_K + (lane >> 4) * 8;
            #pragma unroll 4
            for (int kk = 0; kk < 32; ++kk) {
                f16x8 af = cvt8(*(const f32x8*)(abase + kk * 32));
                const char* bb = bbase + kk * 3072;
                ar = MFMA(af, *(const f16x8*)(bb),       ar);
                az = MFMA(af, *(const f16x8*)(bb + 256), az);
                an = MFMA(af, *(const f16x8*)(bb + 512), an);
            }
        } else {
            const unsigned short* abase = g_hbf + (size_t)(t - 1) * (T_B * T_K)
                + (size_t)(16 * w + (lane & 15)) * T_K + (lane >> 4) * 8;
            // 32-deep preload: all independent loads in flight at once.
            f16x8 af[32];
            #pragma unroll
            for (int kk = 0; kk < 32; ++kk)
                af[kk] = *(const f16x8*)(abase + kk * 32);
            #pragma unroll
            for (int kk = 0; kk < 32; ++kk) {
                const char* bb = bbase + kk * 3072;
                ar = MFMA(af[kk], *(const f16x8*)(bb),       ar);
                az = MFMA(af[kk], *(const f16x8*)(bb + 256), az);
                an = MFMA(af[kk], *(const f16x8*)(bb + 512), an);
            }
        }

        #pragma unroll
        for (int j = 0; j < 4; ++j) {
            int row = 16 * w + (lane >> 4) * 4 + j;
            size_t off = (size_t)row * T_K + colL;
            float hp = (t == 0) ? H0[off] : hreg[j];
            float r = sigmoidf_(pr[j] + ar[j] + br);
            float z = sigmoidf_(pz[j] + az[j] + bz);
            float n = tanhf_(pn[j] + r * (an[j] + bn));
            float h = (1.0f - z) * n + z * hp;
            __half h16 = __float2half(h);         // reference: astype(f16)
            float  hq  = __half2float(h16);
            hreg[j] = hq;
            Y[(size_t)t * (T_B * T_K) + off] = hq;

            // f16 h -> g_hbf via packed u32 relaxed agent store (write-through).
            unsigned v16 = (unsigned)__half_as_ushort(h16);
            unsigned up  = __shfl_xor(v16, 1);
            if (!(lane & 1)) {
                unsigned packed = v16 | (up << 16);
                unsigned* dst = (unsigned*)(g_hbf + (size_t)t * (T_B * T_K) + off);
                __hip_atomic_store(dst, packed, __ATOMIC_RELAXED,
                                   __HIP_MEMORY_SCOPE_AGENT);
            }
        }

        if (t + 1 < T_T) {
            // Drain all vmem (h write-through included), then signal. No fence.
            asm volatile("s_waitcnt vmcnt(0)" ::: "memory");
            __syncthreads();
            if (tid == 0)
                __hip_atomic_store(&g_flags[blockIdx.x * 32], (unsigned)(t + 1),
                                   __ATOMIC_RELAXED, __HIP_MEMORY_SCOPE_AGENT);

            // Prefetch gi for t+1 while polling (normal cached loads).
            const float* g = g_gi + (size_t)(t + 1) * T_B * T_N3;
            #pragma unroll
            for (int j = 0; j < 4; ++j) {
                int row = 16 * w + (lane >> 4) * 4 + j;
                pr[j] = g[(size_t)row * T_N3 + colL];
                pz[j] = g[(size_t)row * T_N3 + 1024 + colL];
                pn[j] = g[(size_t)row * T_N3 + 2048 + colL];
            }

            if (w == 0) {
                unsigned tgt = (unsigned)(t + 1);
                for (;;) {
                    unsigned v = __hip_atomic_load(&g_flags[lane * 32],
                                                   __ATOMIC_RELAXED,
                                                   __HIP_MEMORY_SCOPE_AGENT);
                    if (__all((int)(v >= tgt))) break;
                    __builtin_amdgcn_s_sleep(1);
                }
            }
            asm volatile("" ::: "memory");
            __syncthreads();
        }
    }
}

extern "C" void kernel_launch(void* const* d_in, const int* in_sizes, int n_in,
                              void* d_out, int out_size, void* d_ws, size_t ws_size,
                              hipStream_t stream)
{
    const float* X   = (const float*)d_in[0];
    const float* H0  = (const float*)d_in[1];
    const float* Wih = (const float*)d_in[2];
    const float* Whh = (const float*)d_in[3];
    const float* Bih = (const float*)d_in[4];
    const float* Bhh = (const float*)d_in[5];
    float* Y = (float*)d_out;
    (void)d_ws; (void)ws_size; (void)in_sizes; (void)n_in; (void)out_size;

    reset_flags_k<<<dim3(1), dim3(256), 0, stream>>>();

    gi_gemm<<<dim3(256 * 24), dim3(256), 0, stream>>>(X, Wih, Bih);

    gru_scan<<<dim3(64), dim3(256), 0, stream>>>(Whh, Bhh, H0, Y);
}

// Round 9
// 4404.229 us; speedup vs baseline: 1.7575x; 1.1308x over previous
//
#include <hip/hip_runtime.h>
#include <hip/hip_bf16.h>
#include <hip/hip_fp16.h>

// GRU forward, MI355X. Harness gives f32 buffers (reference f16 -> f32).
// x:(512,64,1024) h0:(1,64,1024) w_ih,w_hh:(3072,1024) b:(3072) y:(512,64,1024).
//
// PROTOCOL (round-2/4/8, thrice-proven bit-deterministic, absmax 0.0078125):
// per-step: gate math writes Y (cached) then h (packed u32 RELAXED
// agent-scope write-through) inside the gate loop; s_waitcnt vmcnt(0);
// __syncthreads; tid0 stores flag (RELAXED agent, PRIVATE 128B line);
// gi prefetch; wave0 gather-polls all 64 flags with s_sleep backoff;
// __syncthreads.
//
// FROZEN BY EXPERIMENT (do not touch any of these):
//  - Y after flag store        -> absmax 0.117 (r3, r6 -- twice)
//  - nontemporal loads/stores  -> absmax 0.117 (r3)
//  - per-band fetch_add sync   -> absmax 0.048 + 7395us (r5)
//  - flags packed 4B stride    -> absmax 0.083 (r7): false sharing of
//    flag lines across non-coherent XCD L2s. 128B padding = correctness.
//
// Round 16 (this round): ONE scheduling-only change vs round 8 (passed):
// pin the 32 h-tile loads with asm ""::: "memory" between issue and the
// MFMA loop. Loads cannot sink past a may-write asm -> all 32 issue
// back-to-back (one ~900cy exposure instead of 4-8 serial ones). VGPR
// should jump 132 -> ~260 (the signal the pin materialized af[32]).
// Round 6 contained this change but failed due to the bundled Y-reorder
// (same 0.117 signature as r3); this is the isolated test.

typedef __attribute__((ext_vector_type(8))) _Float16 f16x8;
typedef __attribute__((ext_vector_type(4))) float f32x4;
typedef __attribute__((ext_vector_type(8))) float f32x8;

#define MFMA(a, b, c) __builtin_amdgcn_mfma_f32_16x16x32_f16((a), (b), (c), 0, 0, 0)

#define T_T 512
#define T_B 64
#define T_K 1024
#define T_N3 3072

__device__ float          g_gi[(size_t)T_T * T_B * T_N3];   // 402 MiB f32 gi
__device__ unsigned short g_hbf[(size_t)T_T * T_B * T_K];   // 64 MiB f16 h_t
__device__ unsigned       g_flags[64 * 32];                 // 128B-padded flags

static __device__ __forceinline__ f16x8 cvt8(f32x8 v) {
    f16x8 r;
    #pragma unroll
    for (int i = 0; i < 8; ++i) r[i] = (_Float16)v[i];
    return r;
}
static __device__ __forceinline__ float sigmoidf_(float x) {
    return 1.0f / (1.0f + __expf(-x));
}
static __device__ __forceinline__ float tanhf_(float x) {
    return 2.0f / (1.0f + __expf(-2.0f * x)) - 1.0f;
}

__global__ __launch_bounds__(256) void reset_flags_k() {
    for (int i = threadIdx.x; i < 64 * 32; i += 256) g_flags[i] = 0;
}

// ---------------------------------------------------------------------------
// Kernel 1: gi = X @ Wih^T + bih, f32 out. f16 MFMA (inputs exactly f16).
// XCD-swizzled blockIdx (bijective: 6144 = 8 * 768).
// ---------------------------------------------------------------------------
__global__ __launch_bounds__(256) void gi_gemm(
    const float* __restrict__ X,     // (32768, 1024) f32
    const float* __restrict__ W,     // (3072, 1024) f32
    const float* __restrict__ bih)   // (3072,) f32
{
    __shared__ unsigned short lA[128 * 32];
    __shared__ unsigned short lB[128 * 32];
    const int tid  = threadIdx.x;
    const int lane = tid & 63;
    const int wid  = tid >> 6;
    const int swz = (blockIdx.x & 7) * 768 + (blockIdx.x >> 3);
    const int m0 = (swz / 24) * 128;
    const int n0 = (swz % 24) * 128;
    const int wm = wid >> 1, wn = wid & 1;

    f32x4 acc[4][4] = {};

    for (int k0 = 0; k0 < T_K; k0 += 32) {
        #pragma unroll
        for (int i = 0; i < 2; ++i) {
            int idx = tid + i * 256;
            int kc  = idx & 3;
            int row = idx >> 2;
            f32x8 va = *(const f32x8*)(X + (size_t)(m0 + row) * T_K + k0 + kc * 8);
            f32x8 vb = *(const f32x8*)(W + (size_t)(n0 + row) * T_K + k0 + kc * 8);
            *(f16x8*)((char*)lA + kc * 2048 + row * 16) = cvt8(va);
            *(f16x8*)((char*)lB + kc * 2048 + row * 16) = cvt8(vb);
        }
        __syncthreads();

        f16x8 a[4], b[4];
        #pragma unroll
        for (int mt = 0; mt < 4; ++mt) {
            int row = 64 * wm + 16 * mt + (lane & 15);
            a[mt] = *(const f16x8*)((const char*)lA + (lane >> 4) * 2048 + row * 16);
        }
        #pragma unroll
        for (int nt = 0; nt < 4; ++nt) {
            int row = 64 * wn + 16 * nt + (lane & 15);
            b[nt] = *(const f16x8*)((const char*)lB + (lane >> 4) * 2048 + row * 16);
        }
        #pragma unroll
        for (int mt = 0; mt < 4; ++mt)
            #pragma unroll
            for (int nt = 0; nt < 4; ++nt)
                acc[mt][nt] = MFMA(a[mt], b[nt], acc[mt][nt]);
        __syncthreads();
    }

    #pragma unroll
    for (int mt = 0; mt < 4; ++mt) {
        int rbase = m0 + 64 * wm + 16 * mt + (lane >> 4) * 4;
        #pragma unroll
        for (int nt = 0; nt < 4; ++nt) {
            int col = n0 + 64 * wn + 16 * nt + (lane & 15);
            float bv = bih[col];
            #pragma unroll
            for (int j = 0; j < 4; ++j)
                g_gi[(size_t)(rbase + j) * T_N3 + col] = acc[mt][nt][j] + bv;
        }
    }
}

// ---------------------------------------------------------------------------
// Kernel 2: persistent GRU scan. 64 blocks x 256 threads, fence-free
// message passing (round-4/8 protocol; ONLY the load-pin asm added).
// ---------------------------------------------------------------------------
__global__ __launch_bounds__(256, 1) void gru_scan(
    const float* __restrict__ Whh,   // (3072,1024) f32
    const float* __restrict__ Bhh,   // (3072,) f32
    const float* __restrict__ H0,    // (64,1024) f32
    float* Y)                        // (512,64,1024) f32
{
    __shared__ unsigned short Wl[48 * 1024];  // 96 KiB f16
    const int tid  = threadIdx.x;
    const int lane = tid & 63;
    const int w    = tid >> 6;
    const int c0   = blockIdx.x * 16;

    for (int idx = tid; idx < 48 * 128; idx += 256) {
        int row = idx >> 7;                   // gate*16 + c
        int kc  = idx & 127;
        int gate = row >> 4, cc = row & 15;
        f32x8 v = *(const f32x8*)(Whh + (size_t)(gate * 1024 + c0 + cc) * T_K + kc * 8);
        *(f16x8*)((char*)Wl + kc * 768 + row * 16) = cvt8(v);
    }
    const int colL = c0 + (lane & 15);
    const float br = Bhh[colL];
    const float bz = Bhh[1024 + colL];
    const float bn = Bhh[2048 + colL];
    __syncthreads();

    const char* bbase = (const char*)Wl + (lane >> 4) * 768 + (lane & 15) * 16;

    // Preload gi for t = 0 (f32, normal cached loads).
    float pr[4], pz[4], pn[4];
    #pragma unroll
    for (int j = 0; j < 4; ++j) {
        int row = 16 * w + (lane >> 4) * 4 + j;
        pr[j] = g_gi[(size_t)row * T_N3 + colL];
        pz[j] = g_gi[(size_t)row * T_N3 + 1024 + colL];
        pn[j] = g_gi[(size_t)row * T_N3 + 2048 + colL];
    }

    // Per-thread h chain registers (f16-rounded values, kept as f32).
    float hreg[4];

    for (int t = 0; t < T_T; ++t) {
        f32x4 ar = {0.f, 0.f, 0.f, 0.f}, az = ar, an = ar;

        if (t == 0) {
            const float* abase =
                H0 + (size_t)(16 * w + (lane & 15)) * T_K + (lane >> 4) * 8;
            #pragma unroll 4
            for (int kk = 0; kk < 32; ++kk) {
                f16x8 af = cvt8(*(const f32x8*)(abase + kk * 32));
                const char* bb = bbase + kk * 3072;
                ar = MFMA(af, *(const f16x8*)(bb),       ar);
                az = MFMA(af, *(const f16x8*)(bb + 256), az);
                an = MFMA(af, *(const f16x8*)(bb + 512), an);
            }
        } else {
            const unsigned short* abase = g_hbf + (size_t)(t - 1) * (T_B * T_K)
                + (size_t)(16 * w + (lane & 15)) * T_K + (lane >> 4) * 8;
            // Issue ALL 32 independent b128 loads, then a may-write asm
            // barrier: loads cannot sink past it -> one latency exposure.
            // Per-use waitcnts below still overlap MFMA with the load tail.
            f16x8 af[32];
            #pragma unroll
            for (int kk = 0; kk < 32; ++kk)
                af[kk] = *(const f16x8*)(abase + kk * 32);
            asm volatile("" ::: "memory");
            #pragma unroll
            for (int kk = 0; kk < 32; ++kk) {
                const char* bb = bbase + kk * 3072;
                ar = MFMA(af[kk], *(const f16x8*)(bb),       ar);
                az = MFMA(af[kk], *(const f16x8*)(bb + 256), az);
                an = MFMA(af[kk], *(const f16x8*)(bb + 512), an);
            }
        }

        #pragma unroll
        for (int j = 0; j < 4; ++j) {
            int row = 16 * w + (lane >> 4) * 4 + j;
            size_t off = (size_t)row * T_K + colL;
            float hp = (t == 0) ? H0[off] : hreg[j];
            float r = sigmoidf_(pr[j] + ar[j] + br);
            float z = sigmoidf_(pz[j] + az[j] + bz);
            float n = tanhf_(pn[j] + r * (an[j] + bn));
            float h = (1.0f - z) * n + z * hp;
            __half h16 = __float2half(h);         // reference: astype(f16)
            float  hq  = __half2float(h16);
            hreg[j] = hq;
            Y[(size_t)t * (T_B * T_K) + off] = hq;

            // f16 h -> g_hbf via packed u32 relaxed agent store (write-through).
            unsigned v16 = (unsigned)__half_as_ushort(h16);
            unsigned up  = __shfl_xor(v16, 1);
            if (!(lane & 1)) {
                unsigned packed = v16 | (up << 16);
                unsigned* dst = (unsigned*)(g_hbf + (size_t)t * (T_B * T_K) + off);
                __hip_atomic_store(dst, packed, __ATOMIC_RELAXED,
                                   __HIP_MEMORY_SCOPE_AGENT);
            }
        }

        if (t + 1 < T_T) {
            // Drain all vmem (h write-through included), then signal. No fence.
            asm volatile("s_waitcnt vmcnt(0)" ::: "memory");
            __syncthreads();
            if (tid == 0)
                __hip_atomic_store(&g_flags[blockIdx.x * 32], (unsigned)(t + 1),
                                   __ATOMIC_RELAXED, __HIP_MEMORY_SCOPE_AGENT);

            // Prefetch gi for t+1 while polling (normal cached loads).
            const float* g = g_gi + (size_t)(t + 1) * T_B * T_N3;
            #pragma unroll
            for (int j = 0; j < 4; ++j) {
                int row = 16 * w + (lane >> 4) * 4 + j;
                pr[j] = g[(size_t)row * T_N3 + colL];
                pz[j] = g[(size_t)row * T_N3 + 1024 + colL];
                pn[j] = g[(size_t)row * T_N3 + 2048 + colL];
            }

            if (w == 0) {
                unsigned tgt = (unsigned)(t + 1);
                for (;;) {
                    unsigned v = __hip_atomic_load(&g_flags[lane * 32],
                                                   __ATOMIC_RELAXED,
                                                   __HIP_MEMORY_SCOPE_AGENT);
                    if (__all((int)(v >= tgt))) break;
                    __builtin_amdgcn_s_sleep(1);
                }
            }
            asm volatile("" ::: "memory");
            __syncthreads();
        }
    }
}

extern "C" void kernel_launch(void* const* d_in, const int* in_sizes, int n_in,
                              void* d_out, int out_size, void* d_ws, size_t ws_size,
                              hipStream_t stream)
{
    const float* X   = (const float*)d_in[0];
    const float* H0  = (const float*)d_in[1];
    const float* Wih = (const float*)d_in[2];
    const float* Whh = (const float*)d_in[3];
    const float* Bih = (const float*)d_in[4];
    const float* Bhh = (const float*)d_in[5];
    float* Y = (float*)d_out;
    (void)d_ws; (void)ws_size; (void)in_sizes; (void)n_in; (void)out_size;

    reset_flags_k<<<dim3(1), dim3(256), 0, stream>>>();

    gi_gemm<<<dim3(256 * 24), dim3(256), 0, stream>>>(X, Wih, Bih);

    gru_scan<<<dim3(64), dim3(256), 0, stream>>>(Whh, Bhh, H0, Y);
}